// Round 3
// baseline (305.768 us; speedup 1.0000x reference)
//
#include <hip/hip_runtime.h>

// Embedding gather: out[i, :] = embeddings[X[i], :]
// X: 4*8192 = 32768 int32 indices; embeddings: 50257 x 1024 fp32.
//
// v2b: 8 rows per block (4096 blocks), 8-deep load pipeline per thread,
// scalar (uniform) index loads, non-temporal output stores so the 134 MB
// streaming write does not evict the ~206 MB L3-resident table.
// Uses clang ext_vector_type (native vector) because
// __builtin_nontemporal_store rejects HIP_vector_type<float,4>.

typedef float f32x4 __attribute__((ext_vector_type(4)));

constexpr int ROWS_PER_BLOCK = 8;

__global__ __launch_bounds__(256) void embedding_gather_kernel(
    const int* __restrict__ X,
    const f32x4* __restrict__ emb,    // viewed as f32x4: row stride = 256
    f32x4* __restrict__ out,          // viewed as f32x4
    int n_rows)
{
    const int t  = threadIdx.x;                    // 256 f32x4 per row
    const int r0 = blockIdx.x * ROWS_PER_BLOCK;

    if (r0 + ROWS_PER_BLOCK <= n_rows) {
        // Uniform (blockIdx-derived) addresses -> compiler emits s_load,
        // one scalar fetch of 8 indices for the whole block.
        int idx[ROWS_PER_BLOCK];
#pragma unroll
        for (int i = 0; i < ROWS_PER_BLOCK; ++i)
            idx[i] = X[r0 + i];

        // 8 independent 16 B gathers in flight per thread (vmcnt 7..0
        // pipelining); stores drain as each load returns.
        f32x4 v[ROWS_PER_BLOCK];
#pragma unroll
        for (int i = 0; i < ROWS_PER_BLOCK; ++i)
            v[i] = emb[(size_t)idx[i] * 256 + t];

#pragma unroll
        for (int i = 0; i < ROWS_PER_BLOCK; ++i)
            __builtin_nontemporal_store(v[i], &out[(size_t)(r0 + i) * 256 + t]);
    } else {
        // Tail (not taken for n_rows = 32768, kept for generality).
        for (int i = 0; i < ROWS_PER_BLOCK; ++i) {
            const int r = r0 + i;
            if (r < n_rows) {
                const int idx = X[r];
                __builtin_nontemporal_store(emb[(size_t)idx * 256 + t],
                                            &out[(size_t)r * 256 + t]);
            }
        }
    }
}

extern "C" void kernel_launch(void* const* d_in, const int* in_sizes, int n_in,
                              void* d_out, int out_size, void* d_ws, size_t ws_size,
                              hipStream_t stream) {
    const int*   X   = (const int*)d_in[0];
    const f32x4* emb = (const f32x4*)d_in[1];
    f32x4*       out = (f32x4*)d_out;
    const int n_rows = in_sizes[0];       // 32768
    const int blocks = (n_rows + ROWS_PER_BLOCK - 1) / ROWS_PER_BLOCK;
    embedding_gather_kernel<<<blocks, 256, 0, stream>>>(X, emb, out, n_rows);
}